// Round 9
// baseline (269.660 us; speedup 1.0000x reference)
//
#include <hip/hip_runtime.h>
#include <hip/hip_bf16.h>

#define HW 128
#define GNUM 2
#define BATCH 4
#define OBT_STRIDE (GNUM * 18 * 2 * 512)   // shorts per hi/lo sub-buffer
#define W3T_FLOATS 331776                  // 663552 shorts
#define OBT_FLOATS 36864                   // 73728 shorts (hi+lo)

typedef short s16x8 __attribute__((ext_vector_type(8)));
typedef float f32x4 __attribute__((ext_vector_type(4)));
typedef float f32x16 __attribute__((ext_vector_type(16)));

__device__ inline unsigned short f2bf(float f) {
    union { float f; unsigned u; } v;
    v.f = f;
    unsigned r = (v.u + 0x7fffu + ((v.u >> 16) & 1u)) >> 16;
    return (unsigned short)r;
}
__device__ inline unsigned pk2bf(float lo, float hi) {   // v_cvt_pk_bf16_f32
    __hip_bfloat162 r = __float22bfloat162_rn(float2{lo, hi});
    return *(unsigned*)&r;
}
__device__ inline float blo(unsigned u) {
    union { unsigned u; float f; } v; v.u = u << 16; return v.f;
}
__device__ inline float bhi(unsigned u) {
    union { unsigned u; float f; } v; v.u = u & 0xffff0000u; return v.f;
}

// ---------------------------------------------------------------------------
// prep_kernel (grid 28 x GNUM):
//   bx 0..8  : W2 table for tap j=bx: w3t[g][j][nh][ks16][lane][i] bf16,
//              W2 = pw_w[kin,f] * dw_w[shift s, kin], B-frag order for
//              mfma_32x32x16 (k = ks16*16 + (lane>>5)*8 + i, n = lane&31,
//              f = nh*32 + n, K-global = s*64 + ch, kin = j*64 + ch).
//   bx 9..26 : obt hi/lo B-frags for the 16x16 offset conv (validated R5-R8).
//   bx 27    : bias2[g][f] = pw_b + sum pw_w*dw_b  (no atomics, no memset).
// ---------------------------------------------------------------------------
__global__ __launch_bounds__(256) void prep_kernel(
    const float* __restrict__ pw_w, const float* __restrict__ dw_w,
    const float* __restrict__ dw_b, const float* __restrict__ off_w,
    const float* __restrict__ pw_b, unsigned short* __restrict__ w3t,
    unsigned short* __restrict__ obt, float* __restrict__ bias2) {
    const int g = blockIdx.y;
    const int t = threadIdx.x;
    const int bx = blockIdx.x;
    if (bx < 9) {
        const int j = bx;
        for (int idx = t; idx < 36864; idx += 256) {
            int i = idx & 7;
            int lane = (idx >> 3) & 63;
            int u = idx >> 9;                 // 0..71 = nh*36 + ks16
            int nh = u / 36, ks16 = u - nh * 36;
            int K = (ks16 << 4) + (((lane >> 5)) << 3) + i;
            int s = K >> 6, ch = K & 63;
            int f = (nh << 5) + (lane & 31);
            float v = pw_w[(g * 576 + (j << 6) + ch) * 64 + f] *
                      dw_w[(g * 9 + s) * 576 + (j << 6) + ch];
            w3t[((((g * 9 + j) << 1) + nh) * 36 + ks16) * 512 + lane * 8 + i] =
                f2bf(v);
        }
    } else if (bx < 27) {
        const int s = bx - 9;
        const int tap = s >> 1;
        for (int e = t; e < 1024; e += 256) {
            int nt = e >> 9, le = e & 511;
            int lane = le >> 3, i = le & 7;
            int k = ((lane >> 4) << 3) + i;
            int c = ((s & 1) << 5) + k;
            int n = (nt << 4) + (lane & 15);
            float v = (n < 18) ? off_w[((g * 9 + tap) * 64 + c) * 18 + n] : 0.f;
            unsigned short hi = f2bf(v);
            unsigned short lo = f2bf(v - blo(hi));
            int idx = (((g * 18 + s) * 2 + nt) << 9) + le;
            obt[idx] = hi;
            obt[OBT_STRIDE + idx] = lo;
        }
    } else {
        if (t < 64) {
            const int f = t;
            float acc = pw_b[g * 64 + f];
            for (int kin = 0; kin < 576; ++kin)
                acc += pw_w[(g * 576 + kin) * 64 + f] * dw_b[g * 576 + kin];
            bias2[g * 64 + f] = acc;
        }
    }
}

// ---------------------------------------------------------------------------
// deform_fused: per 8x8 output tile of (b,g):
//   Stage 0: offset conv (3x3 SAME 64->18, split-precision 16x16 bf16 MFMA,
//            validated R5-R8) for the 10x10 halo -> offs[] in LDS.
//   Stage 1 per tap j: W (bilinear wts) -> S (float4 gather) ->
//            B' (depthwise+pointwise folded GEMM, 32x32x16 MFMA, K=576:
//            9 shifts x 64 ch, B = precomputed pw*dw table).
// LDS (27936 B -> 5 blocks/CU):
//   [0,20736)     xh ushort[144*72] (stage 0)  ALIASED WITH stage 1:
//                 samp ushort[100*72] @0 ; wlw float4[100] @14400 ;
//                 wli int2[100] @16000
//   [20736,27936) offs float[100*18]   (written stage 0, read stage 1)
// ---------------------------------------------------------------------------
__global__ __launch_bounds__(256, 5) void deform_fused(
    const float* __restrict__ x, const unsigned short* __restrict__ obt,
    const float* __restrict__ off_b, const unsigned short* __restrict__ w3t,
    const float* __restrict__ bias2, float* __restrict__ out) {
    __shared__ char smem[27936];
    unsigned short* xh = (unsigned short*)smem;           // stage 0
    unsigned short* samp = (unsigned short*)smem;         // stage 1
    float4* wlw = (float4*)(smem + 14400);
    int2* wli = (int2*)(smem + 16000);
    float* offs = (float*)(smem + 20736);

    const int b = blockIdx.x >> 1, g = blockIdx.x & 1;
    const int tileIdx = blockIdx.y;
    const int h0 = (tileIdx >> 4) << 3, w0 = (tileIdx & 15) << 3;
    const int t = threadIdx.x;
    const int lane = t & 63;
    const int wv = __builtin_amdgcn_readfirstlane(t >> 6);

    // ================= Stage 0: offset conv for the halo (16x16 MFMA) ====
    {
        const int kq = (lane >> 4) << 3;
        const int col = lane & 15;
        const int rq = (lane >> 4) << 2;
        f32x4 oacc[2][2];
#pragma unroll
        for (int sl = 0; sl < 2; ++sl)
#pragma unroll
            for (int nt = 0; nt < 2; ++nt)
                oacc[sl][nt] = (f32x4){0.f, 0.f, 0.f, 0.f};
        int mbase[2];
#pragma unroll
        for (int sl = 0; sl < 2; ++sl) {
            int mt = wv + (sl << 2);
            int m = mt * 16 + col;
            if (mt < 7 && m < 100) {
                int opy = m / 10, opx = m - opy * 10;
                mbase[sl] = opy * 12 + opx;
            } else
                mbase[sl] = 0;
        }
        for (int q = 0; q < 2; ++q) {
            if (q) __syncthreads();
            for (int idx = t; idx < 144 * 8; idx += 256) {
                int sp = idx >> 3, cq = idx & 7;
                int sy = sp / 12, sx = sp - sy * 12;
                int gy = h0 - 2 + sy, gx = w0 - 2 + sx;
                uint2 hp = {0, 0}, lp = {0, 0};
                if ((unsigned)gy < HW && (unsigned)gx < HW) {
                    const float4 v = *(const float4*)&x
                        [(((b * HW + gy) * HW + gx) << 7) + (g << 6) +
                         (q << 5) + (cq << 2)];
                    hp.x = pk2bf(v.x, v.y);
                    hp.y = pk2bf(v.z, v.w);
                    lp.x = pk2bf(v.x - blo(hp.x), v.y - bhi(hp.x));
                    lp.y = pk2bf(v.z - blo(hp.y), v.w - bhi(hp.y));
                }
                *(uint2*)&xh[sp * 72 + (cq << 2)] = hp;
                *(uint2*)&xh[sp * 72 + 32 + (cq << 2)] = lp;
            }
            __syncthreads();
            for (int tap = 0; tap < 9; ++tap) {
                const int s = (tap << 1) + q;
                const int ky = tap / 3, kx = tap - ky * 3;
                const int shift = ky * 12 + kx;
                const int bidx = ((g * 18 + s) << 1) << 9;
                s16x8 bh0 = *(const s16x8*)&obt[bidx + lane * 8];
                s16x8 bh1 = *(const s16x8*)&obt[bidx + 512 + lane * 8];
                s16x8 bl0 = *(const s16x8*)&obt[OBT_STRIDE + bidx + lane * 8];
                s16x8 bl1 =
                    *(const s16x8*)&obt[OBT_STRIDE + bidx + 512 + lane * 8];
#pragma unroll
                for (int sl = 0; sl < 2; ++sl) {
                    if (wv + (sl << 2) < 7) {
                        const int base2 = (mbase[sl] + shift) * 72 + kq;
                        s16x8 ah = *(const s16x8*)&xh[base2];
                        s16x8 al = *(const s16x8*)&xh[base2 + 32];
                        oacc[sl][0] = __builtin_amdgcn_mfma_f32_16x16x32_bf16(
                            ah, bh0, oacc[sl][0], 0, 0, 0);
                        oacc[sl][1] = __builtin_amdgcn_mfma_f32_16x16x32_bf16(
                            ah, bh1, oacc[sl][1], 0, 0, 0);
                        oacc[sl][0] = __builtin_amdgcn_mfma_f32_16x16x32_bf16(
                            al, bh0, oacc[sl][0], 0, 0, 0);
                        oacc[sl][1] = __builtin_amdgcn_mfma_f32_16x16x32_bf16(
                            al, bh1, oacc[sl][1], 0, 0, 0);
                        oacc[sl][0] = __builtin_amdgcn_mfma_f32_16x16x32_bf16(
                            ah, bl0, oacc[sl][0], 0, 0, 0);
                        oacc[sl][1] = __builtin_amdgcn_mfma_f32_16x16x32_bf16(
                            ah, bl1, oacc[sl][1], 0, 0, 0);
                    }
                }
            }
        }
#pragma unroll
        for (int sl = 0; sl < 2; ++sl) {
            int mt = wv + (sl << 2);
            if (mt < 7) {
#pragma unroll
                for (int nt = 0; nt < 2; ++nt) {
                    int o = (nt << 4) + col;
                    if (o < 18) {
                        float ob = off_b[g * 18 + o];
#pragma unroll
                        for (int i = 0; i < 4; ++i) {
                            int m = mt * 16 + rq + i;
                            if (m < 100)
                                offs[m * 18 + o] = oacc[sl][nt][i] + ob;
                        }
                    }
                }
            }
        }
    }
    __syncthreads();   // offs visible; all xh reads done before samp reuse

    // ================= Stage 1: sample -> folded GEMM ====================
    const int mh = wv >> 1, nh = wv & 1;          // wave -> (px-half, f-half)
    const int p32 = (mh << 5) + (lane & 31);      // pixel 0..63
    const int pr = p32 >> 3, pc = p32 & 7;
    const int kq8 = (lane >> 5) << 3;
    const int fcol = (nh << 5) + (lane & 31);
    const int grp = t >> 4, sl16 = t & 15;

    const float bs = bias2[g * 64 + fcol];
    f32x16 acc;
#pragma unroll
    for (int i = 0; i < 16; ++i) acc[i] = bs;

    for (int j = 0; j < 9; ++j) {
        const int jy = j / 3, jx = j - jy * 3;
        // ---- Phase W: bilinear weights + corner offsets, one thread per sp
        if (t < 100) {
            const int sp = t;
            const int spy = sp / 10, spx = sp - spy * 10;
            const int gy = h0 - 1 + spy, gx = w0 - 1 + spx;
            float4 w4 = {0.f, 0.f, 0.f, 0.f};
            int2 ii = {b << 21, 0};
            if ((unsigned)gy < HW && (unsigned)gx < HW) {
                const float2 o2 = *(const float2*)&offs[sp * 18 + 2 * j];
                float xf = fminf(fmaxf((float)(gx + jx - 1) + o2.x, 0.f), 127.f);
                float yf = fminf(fmaxf((float)(gy + jy - 1) + o2.y, 0.f), 127.f);
                float x0 = floorf(xf), y0 = floorf(yf);
                float x1 = fminf(x0 + 1.f, 127.f);
                float y1 = fminf(y0 + 1.f, 127.f);
                w4.x = (x1 - xf) * (y1 - yf);
                w4.y = (x1 - xf) * (yf - y0);
                w4.z = (xf - x0) * (y1 - yf);
                w4.w = (xf - x0) * (yf - y0);
                const int x0i = (int)x0, y0i = (int)y0;
                ii.x = ((b * HW + y0i) * HW + x0i) << 7;
                ii.y = ((int)x1 - x0i) | (((int)y1 - y0i) << 1);
            }
            wlw[sp] = w4;
            wli[sp] = ii;
        }
        __syncthreads();
        // ---- Phase S: float4 gather; 16 lanes per sample position
        for (int it = 0; it < 7; ++it) {
            const int sp = (it << 4) + grp;
            if (sp < 100) {
                const float4 w4 = wlw[sp];
                const int2 ii = wli[sp];
                const int dxo = (ii.y & 1) << 7;
                const int dyo = (ii.y & 2) << 13;
                const float* xa = x + ii.x + (g << 6) + (sl16 << 2);
                const float4 va = *(const float4*)xa;
                const float4 vb = *(const float4*)(xa + dyo);
                const float4 vc = *(const float4*)(xa + dxo);
                const float4 vd = *(const float4*)(xa + dxo + dyo);
                float r0 = w4.x * va.x + w4.y * vb.x + w4.z * vc.x + w4.w * vd.x;
                float r1 = w4.x * va.y + w4.y * vb.y + w4.z * vc.y + w4.w * vd.y;
                float r2 = w4.x * va.z + w4.y * vb.z + w4.z * vc.z + w4.w * vd.z;
                float r3 = w4.x * va.w + w4.y * vb.w + w4.z * vc.w + w4.w * vd.w;
                uint2 pk;
                pk.x = pk2bf(r0, r1);
                pk.y = pk2bf(r2, r3);
                *(uint2*)&samp[sp * 72 + (sl16 << 2)] = pk;
            }
        }
        __syncthreads();
        // ---- Phase B': folded depthwise+pointwise GEMM, K = 9 shifts x 64
        const unsigned short* w3 =
            &w3t[((((g * 9 + j) << 1) + nh) * 36) * 512 + lane * 8];
#pragma unroll
        for (int s = 0; s < 9; ++s) {
            const int ky = s / 3, kx = s - ky * 3;
            const int abase = ((pr + ky) * 10 + pc + kx) * 72 + kq8;
#pragma unroll
            for (int chunk = 0; chunk < 4; ++chunk) {
                s16x8 af = *(const s16x8*)&samp[abase + (chunk << 4)];
                s16x8 bf = *(const s16x8*)&w3[((s << 2) + chunk) << 9];
                acc = __builtin_amdgcn_mfma_f32_32x32x16_bf16(af, bf, acc, 0,
                                                              0, 0);
            }
        }
    }
    // ---- epilogue: 32x32 C-layout col=lane&31, row=(r&3)+8*(r>>2)+4*(l>>5)
    const int rbase = (lane >> 5) << 2;
#pragma unroll
    for (int r = 0; r < 16; ++r) {
        int row = (r & 3) + ((r >> 2) << 3) + rbase;
        int pp = (mh << 5) + row;
        out[((b * HW + h0 + (pp >> 3)) * HW + (w0 + (pp & 7))) * 128 +
            (g << 6) + fcol] = acc[r];
    }
}

extern "C" void kernel_launch(void* const* d_in, const int* in_sizes, int n_in,
                              void* d_out, int out_size, void* d_ws,
                              size_t ws_size, hipStream_t stream) {
    const float* x = (const float*)d_in[0];
    const float* off_w = (const float*)d_in[1];
    const float* off_b = (const float*)d_in[2];
    const float* dw_w = (const float*)d_in[3];
    const float* dw_b = (const float*)d_in[4];
    const float* pw_w = (const float*)d_in[5];
    const float* pw_b = (const float*)d_in[6];

    // workspace layout (floats): [w3t | obt | bias2]
    float* wsf = (float*)d_ws;
    unsigned short* w3t = (unsigned short*)wsf;                // 1327104 B
    unsigned short* obt = (unsigned short*)(wsf + W3T_FLOATS); // 147456 B
    float* bias2 = wsf + W3T_FLOATS + OBT_FLOATS;              // 512 B

    prep_kernel<<<dim3(28, GNUM), dim3(256), 0, stream>>>(
        pw_w, dw_w, dw_b, off_w, pw_b, w3t, obt, bias2);
    deform_fused<<<dim3(BATCH * GNUM, 256), dim3(256), 0, stream>>>(
        x, obt, off_b, w3t, bias2, (float*)d_out);
}